// Round 1
// baseline (322.649 us; speedup 1.0000x reference)
//
#include <hip/hip_runtime.h>
#include <math.h>

#define Bg   64
#define Nn   1024
#define Dd   256
#define Ee   (Bg * Nn * 16)      // 1048576 edges
#define NT   (Bg * Nn)           // 65536 nodes
#define Kk   512

// d_out float offsets
#define OFF_DIS   0
#define OFF_COM   8388608
#define OFF_PERM  16777216
#define OFF_PCOM  16809984
#define OFF_SOFT  16842752

// ws byte offsets (agg, deg_out, deg_in contiguous for one memset)
#define WS_AGG     0
#define WS_DEGOUT  (NT * 4)
#define WS_DEGIN   (NT * 4 * 2)
#define WS_H0      (NT * 4 * 3)
#define WS_SFLAT   (NT * 4 * 4)
#define WS_GPART   (NT * 4 * 5)            // 512 blocks * 256 floats = 512 KB
#define WS_C0      (WS_GPART + 512 * 256 * 4)
#define WS_C1      (WS_C0 + 1024)
#define WS_RED     (WS_C1 + 1024)
#define WS_PERMI   (WS_RED + 256)
#define WS_PCOMI   (WS_PERMI + 32768 * 4)

__global__ void k_deg(const int* __restrict__ src, const int* __restrict__ dst,
                      int* __restrict__ deg_out, int* __restrict__ deg_in) {
    int e = blockIdx.x * blockDim.x + threadIdx.x;
    if (e < Ee) {
        atomicAdd(&deg_out[src[e]], 1);
        atomicAdd(&deg_in[dst[e]], 1);
    }
}

// 512 blocks x 256 threads; each block: 128 rows of one graph slice.
// Part A: per-column partial sums -> gpart. Part B: h0[row] = dot(feature[row], W).
__global__ void k_pass1(const float* __restrict__ f, const float* __restrict__ W,
                        float* __restrict__ gpart, float* __restrict__ h0) {
    int blk  = blockIdx.x;
    int base = blk * 128;
    int t    = threadIdx.x;
    // Part A: column sums (coalesced across threads)
    float s = 0.f;
    const float* fp = f + (size_t)base * Dd + t;
    for (int r = 0; r < 128; ++r) s += fp[(size_t)r * Dd];
    gpart[blk * Dd + t] = s;
    // Part B: wave-per-row dot with W
    int lane = t & 63, wid = t >> 6;
    const float4* f4 = (const float4*)f;
    const float4* W4 = (const float4*)W;
    float4 w = W4[lane];
    for (int r = 0; r < 32; ++r) {
        int row = base + wid * 32 + r;
        float4 v = f4[(size_t)row * 64 + lane];
        float d = v.x * w.x + v.y * w.y + v.z * w.z + v.w * w.w;
        for (int o = 32; o > 0; o >>= 1) d += __shfl_xor(d, o);
        if (lane == 0) h0[row] = d;
    }
}

// 1 block x 256 threads: reduce partials -> gemb -> class centers (deterministic)
__global__ void k_centers(const float* __restrict__ gpart, const int* __restrict__ label,
                          float* __restrict__ c0, float* __restrict__ c1) {
    int t = threadIdx.x;
    int n1 = 0;
    for (int g = 0; g < Bg; ++g) n1 += label[g];
    float fn1 = fmaxf((float)n1, 1.f);
    float fn0 = fmaxf((float)(Bg - n1), 1.f);
    float s0 = 0.f, s1 = 0.f;
    for (int g = 0; g < Bg; ++g) {
        float v = 0.f;
        for (int p = 0; p < 8; ++p) v += gpart[(g * 8 + p) * Dd + t];
        v *= (1.f / (float)Nn);               // gemb
        if (label[g]) s1 += v; else s0 += v;
    }
    c0[t] = s0 / fn0;
    c1[t] = s1 / fn1;
}

__global__ void k_scatter(const int* __restrict__ src, const int* __restrict__ dst,
                          const float* __restrict__ h0, const int* __restrict__ deg_out,
                          float* __restrict__ agg) {
    int e = blockIdx.x * blockDim.x + threadIdx.x;
    if (e < Ee) {
        int s = src[e], d = dst[e];
        int dg = deg_out[s]; if (dg < 1) dg = 1;
        float ns = 1.f / sqrtf((float)dg);
        atomicAdd(&agg[d], h0[s] * ns);
    }
}

// wave-per-node: distances to centers + combine scores
__global__ void k_score(const float* __restrict__ f, const float* __restrict__ c0,
                        const float* __restrict__ c1, const float* __restrict__ agg,
                        const int* __restrict__ deg_in, const int* __restrict__ label,
                        const float* __restrict__ b, const float* __restrict__ lw,
                        const float* __restrict__ lb, float* __restrict__ sflat) {
    int node = blockIdx.x * 4 + (threadIdx.x >> 6);
    int lane = threadIdx.x & 63;
    const float4* f4  = (const float4*)f;
    const float4* c04 = (const float4*)c0;
    const float4* c14 = (const float4*)c1;
    float4 v = f4[(size_t)node * 64 + lane];
    float4 a = c04[lane];
    float4 bb = c14[lane];
    float dx, acc0, acc1;
    dx = v.x - a.x;  acc0  = dx * dx;
    dx = v.y - a.y;  acc0 += dx * dx;
    dx = v.z - a.z;  acc0 += dx * dx;
    dx = v.w - a.w;  acc0 += dx * dx;
    dx = v.x - bb.x; acc1  = dx * dx;
    dx = v.y - bb.y; acc1 += dx * dx;
    dx = v.z - bb.z; acc1 += dx * dx;
    dx = v.w - bb.w; acc1 += dx * dx;
    for (int o = 32; o > 0; o >>= 1) {
        acc0 += __shfl_xor(acc0, o);
        acc1 += __shfl_xor(acc1, o);
    }
    if (lane == 0) {
        float d0 = sqrtf(acc0), d1 = sqrtf(acc1);
        int g = node >> 10;
        float sgn = label[g] ? 1.f : -1.f;
        float sdist = (d0 - d1) * sgn;
        int dg = deg_in[node]; if (dg < 1) dg = 1;
        float nd = 1.f / sqrtf((float)dg);
        float sg = agg[node] * nd + b[0];
        sflat[node] = sg * lw[0] + sdist * lw[1] + lb[0];
    }
}

// one block (1024 threads) per graph: bitonic sort desc (idx-asc tiebreak),
// emit perm (sorted top-K) + perm_com (ascending complement via scan)
__global__ void k_topk(const float* __restrict__ sflat, int* __restrict__ permI,
                       int* __restrict__ pcomI, float* __restrict__ out) {
    __shared__ float sv[1024];
    __shared__ int   si[1024];
    __shared__ int   sflag[1024];
    __shared__ int   sscan[1024];
    int g = blockIdx.x, t = threadIdx.x;
    sv[t] = sflat[g * Nn + t];
    si[t] = t;
    __syncthreads();
    for (int k = 2; k <= 1024; k <<= 1) {
        for (int j = k >> 1; j > 0; j >>= 1) {
            int ixj = t ^ j;
            if (ixj > t) {
                float v1 = sv[t], v2 = sv[ixj];
                int i1 = si[t], i2 = si[ixj];
                // key = (-value, index); gt == should come later ascending-in-key
                bool gt = (v1 < v2) || (v1 == v2 && i1 > i2);
                bool up = ((t & k) == 0);
                if (gt == up) { sv[t] = v2; sv[ixj] = v1; si[t] = i2; si[ixj] = i1; }
            }
            __syncthreads();
        }
    }
    sflag[t] = 1;
    __syncthreads();
    if (t < Kk) {
        int loc = si[t];
        sflag[loc] = 0;
        int gi = g * Nn + loc;
        permI[g * Kk + t] = gi;
        out[OFF_PERM + g * Kk + t] = (float)gi;
    }
    __syncthreads();
    int x = sflag[t];
    sscan[t] = x;
    __syncthreads();
    for (int o = 1; o < 1024; o <<= 1) {
        int add = (t >= o) ? sscan[t - o] : 0;
        __syncthreads();
        sscan[t] += add;
        __syncthreads();
    }
    if (x) {
        int pos = sscan[t] - 1;              // exclusive position among unselected
        int gi = g * Nn + t;
        pcomI[g * Kk + pos] = gi;
        out[OFF_PCOM + g * Kk + pos] = (float)gi;
    }
}

__global__ void k_softred(const float* __restrict__ sflat, float* __restrict__ red) {
    __shared__ float sm[1024];
    int t = threadIdx.x;
    float m = -INFINITY;
    for (int i = t; i < NT; i += 1024) m = fmaxf(m, sflat[i]);
    sm[t] = m;
    __syncthreads();
    for (int o = 512; o > 0; o >>= 1) {
        if (t < o) sm[t] = fmaxf(sm[t], sm[t + o]);
        __syncthreads();
    }
    m = sm[0];
    __syncthreads();
    float s = 0.f;
    for (int i = t; i < NT; i += 1024) s += expf(sflat[i] - m);
    sm[t] = s;
    __syncthreads();
    for (int o = 512; o > 0; o >>= 1) {
        if (t < o) sm[t] += sm[t + o];
        __syncthreads();
    }
    if (t == 0) { red[0] = m; red[1] = sm[0]; }
}

__global__ void k_softwrite(const float* __restrict__ sflat, const float* __restrict__ red,
                            float* __restrict__ out) {
    int i = blockIdx.x * blockDim.x + threadIdx.x;
    if (i < NT) out[OFF_SOFT + i] = expf(sflat[i] - red[0]) / red[1];
}

// wave-per-output-row gather: feature[row] * tanh(sflat[row])
__global__ void k_gather(const float* __restrict__ f, const int* __restrict__ permI,
                         const int* __restrict__ pcomI, const float* __restrict__ sflat,
                         float* __restrict__ out) {
    int j = blockIdx.x * 4 + (threadIdx.x >> 6);   // 0..65535
    int lane = threadIdx.x & 63;
    int row = (j < 32768) ? permI[j] : pcomI[j - 32768];
    float tv = tanhf(sflat[row]);
    const float4* f4 = (const float4*)f;
    float4* o4 = (float4*)out;                      // dis at row 0, com right after
    float4 v = f4[(size_t)row * 64 + lane];
    o4[(size_t)j * 64 + lane] = make_float4(v.x * tv, v.y * tv, v.z * tv, v.w * tv);
}

extern "C" void kernel_launch(void* const* d_in, const int* in_sizes, int n_in,
                              void* d_out, int out_size, void* d_ws, size_t ws_size,
                              hipStream_t stream) {
    const float* feature = (const float*)d_in[0];
    const int*   src     = (const int*)d_in[1];
    const int*   dst     = (const int*)d_in[2];
    const int*   label   = (const int*)d_in[3];
    const float* W       = (const float*)d_in[4];
    const float* b       = (const float*)d_in[5];
    const float* lw      = (const float*)d_in[6];
    const float* lb      = (const float*)d_in[7];
    float* out = (float*)d_out;
    char*  ws  = (char*)d_ws;

    float* agg     = (float*)(ws + WS_AGG);
    int*   deg_out = (int*)(ws + WS_DEGOUT);
    int*   deg_in  = (int*)(ws + WS_DEGIN);
    float* h0      = (float*)(ws + WS_H0);
    float* sflat   = (float*)(ws + WS_SFLAT);
    float* gpart   = (float*)(ws + WS_GPART);
    float* c0      = (float*)(ws + WS_C0);
    float* c1      = (float*)(ws + WS_C1);
    float* red     = (float*)(ws + WS_RED);
    int*   permI   = (int*)(ws + WS_PERMI);
    int*   pcomI   = (int*)(ws + WS_PCOMI);

    // zero agg + deg_out + deg_in in one shot
    hipMemsetAsync(ws + WS_AGG, 0, NT * 4 * 3, stream);

    k_deg<<<Ee / 256, 256, 0, stream>>>(src, dst, deg_out, deg_in);
    k_pass1<<<512, 256, 0, stream>>>(feature, W, gpart, h0);
    k_centers<<<1, 256, 0, stream>>>(gpart, label, c0, c1);
    k_scatter<<<Ee / 256, 256, 0, stream>>>(src, dst, h0, deg_out, agg);
    k_score<<<NT / 4, 256, 0, stream>>>(feature, c0, c1, agg, deg_in, label, b, lw, lb, sflat);
    k_topk<<<Bg, 1024, 0, stream>>>(sflat, permI, pcomI, out);
    k_softred<<<1, 1024, 0, stream>>>(sflat, red);
    k_softwrite<<<NT / 256, 256, 0, stream>>>(sflat, red, out);
    k_gather<<<NT / 4, 256, 0, stream>>>(feature, permI, pcomI, sflat, out);
}

// Round 2
// 258.471 us; speedup vs baseline: 1.2483x; 1.2483x over previous
//
#include <hip/hip_runtime.h>
#include <math.h>

#define Bg   64
#define Nn   1024
#define Dd   256
#define Ee   (Bg * Nn * 16)      // 1048576 edges
#define EPG  16384               // edges per graph
#define NT   (Bg * Nn)           // 65536 nodes
#define Kk   512

// d_out float offsets
#define OFF_DIS   0
#define OFF_COM   8388608
#define OFF_PERM  16777216
#define OFF_PCOM  16809984
#define OFF_SOFT  16842752

// ws byte offsets
#define WS_SGCN    0                       // NT floats: score_gcn (finished)
#define WS_H0      (NT * 4)
#define WS_SFLAT   (NT * 4 * 2)
#define WS_GPART   (NT * 4 * 3)            // 512 blocks * 256 floats
#define WS_C0      (WS_GPART + 512 * 256 * 4)
#define WS_C1      (WS_C0 + 1024)
#define WS_RED     (WS_C1 + 1024)
#define WS_PERMI   (WS_RED + 256)
#define WS_PCOMI   (WS_PERMI + 32768 * 4)

// 512 blocks x 256 threads; each block: 128 rows of one graph slice.
// Part A: per-column partial sums -> gpart. Part B: h0[row] = dot(feature[row], W).
__global__ void k_pass1(const float* __restrict__ f, const float* __restrict__ W,
                        float* __restrict__ gpart, float* __restrict__ h0) {
    int blk  = blockIdx.x;
    int base = blk * 128;
    int t    = threadIdx.x;
    float s = 0.f;
    const float* fp = f + (size_t)base * Dd + t;
    for (int r = 0; r < 128; ++r) s += fp[(size_t)r * Dd];
    gpart[blk * Dd + t] = s;
    int lane = t & 63, wid = t >> 6;
    const float4* f4 = (const float4*)f;
    const float4* W4 = (const float4*)W;
    float4 w = W4[lane];
    for (int r = 0; r < 32; ++r) {
        int row = base + wid * 32 + r;
        float4 v = f4[(size_t)row * 64 + lane];
        float d = v.x * w.x + v.y * w.y + v.z * w.z + v.w * w.w;
        for (int o = 32; o > 0; o >>= 1) d += __shfl_xor(d, o);
        if (lane == 0) h0[row] = d;
    }
}

// 1 block x 256 threads: reduce partials -> gemb -> class centers (deterministic)
__global__ void k_centers(const float* __restrict__ gpart, const int* __restrict__ label,
                          float* __restrict__ c0, float* __restrict__ c1) {
    int t = threadIdx.x;
    int n1 = 0;
    for (int g = 0; g < Bg; ++g) n1 += label[g];
    float fn1 = fmaxf((float)n1, 1.f);
    float fn0 = fmaxf((float)(Bg - n1), 1.f);
    float s0 = 0.f, s1 = 0.f;
    for (int g = 0; g < Bg; ++g) {
        float v = 0.f;
        for (int p = 0; p < 8; ++p) v += gpart[(g * 8 + p) * Dd + t];
        v *= (1.f / (float)Nn);
        if (label[g]) s1 += v; else s0 += v;
    }
    c0[t] = s0 / fn0;
    c1[t] = s1 / fn1;
}

// One block per graph: degree count + normalized scatter, all in LDS.
// Emits finished score_gcn = agg*nd + b.
__global__ __launch_bounds__(1024) void k_edges(
        const int* __restrict__ src, const int* __restrict__ dst,
        const float* __restrict__ h0, const float* __restrict__ b,
        float* __restrict__ sgcn) {
    __shared__ ushort2 eb[EPG];        // local (src,dst) per edge: 64 KB
    __shared__ int   sdo[Nn];          // deg_out
    __shared__ int   sdi[Nn];          // deg_in
    __shared__ float sagg[Nn];
    __shared__ float shn[Nn];          // h0 * ns
    int g = blockIdx.x, t = threadIdx.x;
    sdo[t] = 0; sdi[t] = 0; sagg[t] = 0.f;
    __syncthreads();
    int ebase = g * EPG;
    #pragma unroll
    for (int i = t; i < EPG; i += 1024) {
        int s = src[ebase + i] & (Nn - 1);
        int d = dst[ebase + i] & (Nn - 1);
        eb[i] = make_ushort2((unsigned short)s, (unsigned short)d);
        atomicAdd(&sdo[s], 1);
        atomicAdd(&sdi[d], 1);
    }
    __syncthreads();
    {
        int dg = sdo[t]; if (dg < 1) dg = 1;
        shn[t] = h0[g * Nn + t] / sqrtf((float)dg);
    }
    __syncthreads();
    #pragma unroll
    for (int i = t; i < EPG; i += 1024) {
        ushort2 e = eb[i];
        atomicAdd(&sagg[e.y], shn[e.x]);
    }
    __syncthreads();
    {
        int dg = sdi[t]; if (dg < 1) dg = 1;
        float nd = 1.f / sqrtf((float)dg);
        sgcn[g * Nn + t] = sagg[t] * nd + b[0];
    }
}

// wave-per-node: distances to centers + combine scores
__global__ void k_score(const float* __restrict__ f, const float* __restrict__ c0,
                        const float* __restrict__ c1, const float* __restrict__ sgcn,
                        const int* __restrict__ label, const float* __restrict__ lw,
                        const float* __restrict__ lb, float* __restrict__ sflat) {
    int node = blockIdx.x * 4 + (threadIdx.x >> 6);
    int lane = threadIdx.x & 63;
    const float4* f4  = (const float4*)f;
    const float4* c04 = (const float4*)c0;
    const float4* c14 = (const float4*)c1;
    float4 v = f4[(size_t)node * 64 + lane];
    float4 a = c04[lane];
    float4 bb = c14[lane];
    float dx, acc0, acc1;
    dx = v.x - a.x;  acc0  = dx * dx;
    dx = v.y - a.y;  acc0 += dx * dx;
    dx = v.z - a.z;  acc0 += dx * dx;
    dx = v.w - a.w;  acc0 += dx * dx;
    dx = v.x - bb.x; acc1  = dx * dx;
    dx = v.y - bb.y; acc1 += dx * dx;
    dx = v.z - bb.z; acc1 += dx * dx;
    dx = v.w - bb.w; acc1 += dx * dx;
    for (int o = 32; o > 0; o >>= 1) {
        acc0 += __shfl_xor(acc0, o);
        acc1 += __shfl_xor(acc1, o);
    }
    if (lane == 0) {
        float d0 = sqrtf(acc0), d1 = sqrtf(acc1);
        int g = node >> 10;
        float sgn = label[g] ? 1.f : -1.f;
        float sdist = (d0 - d1) * sgn;
        sflat[node] = sgcn[node] * lw[0] + sdist * lw[1] + lb[0];
    }
}

// one block (1024 threads) per graph: bitonic sort desc (idx-asc tiebreak),
// emit perm (sorted top-K) + perm_com (ascending complement via scan)
__global__ void k_topk(const float* __restrict__ sflat, int* __restrict__ permI,
                       int* __restrict__ pcomI, float* __restrict__ out) {
    __shared__ float sv[1024];
    __shared__ int   si[1024];
    __shared__ int   sflag[1024];
    __shared__ int   sscan[1024];
    int g = blockIdx.x, t = threadIdx.x;
    sv[t] = sflat[g * Nn + t];
    si[t] = t;
    __syncthreads();
    for (int k = 2; k <= 1024; k <<= 1) {
        for (int j = k >> 1; j > 0; j >>= 1) {
            int ixj = t ^ j;
            if (ixj > t) {
                float v1 = sv[t], v2 = sv[ixj];
                int i1 = si[t], i2 = si[ixj];
                bool gt = (v1 < v2) || (v1 == v2 && i1 > i2);
                bool up = ((t & k) == 0);
                if (gt == up) { sv[t] = v2; sv[ixj] = v1; si[t] = i2; si[ixj] = i1; }
            }
            __syncthreads();
        }
    }
    sflag[t] = 1;
    __syncthreads();
    if (t < Kk) {
        int loc = si[t];
        sflag[loc] = 0;
        int gi = g * Nn + loc;
        permI[g * Kk + t] = gi;
        out[OFF_PERM + g * Kk + t] = (float)gi;
    }
    __syncthreads();
    int x = sflag[t];
    sscan[t] = x;
    __syncthreads();
    for (int o = 1; o < 1024; o <<= 1) {
        int add = (t >= o) ? sscan[t - o] : 0;
        __syncthreads();
        sscan[t] += add;
        __syncthreads();
    }
    if (x) {
        int pos = sscan[t] - 1;
        int gi = g * Nn + t;
        pcomI[g * Kk + pos] = gi;
        out[OFF_PCOM + g * Kk + pos] = (float)gi;
    }
}

__global__ void k_softred(const float* __restrict__ sflat, float* __restrict__ red) {
    __shared__ float sm[1024];
    int t = threadIdx.x;
    float m = -INFINITY;
    for (int i = t; i < NT; i += 1024) m = fmaxf(m, sflat[i]);
    sm[t] = m;
    __syncthreads();
    for (int o = 512; o > 0; o >>= 1) {
        if (t < o) sm[t] = fmaxf(sm[t], sm[t + o]);
        __syncthreads();
    }
    m = sm[0];
    __syncthreads();
    float s = 0.f;
    for (int i = t; i < NT; i += 1024) s += expf(sflat[i] - m);
    sm[t] = s;
    __syncthreads();
    for (int o = 512; o > 0; o >>= 1) {
        if (t < o) sm[t] += sm[t + o];
        __syncthreads();
    }
    if (t == 0) { red[0] = m; red[1] = sm[0]; }
}

__global__ void k_softwrite(const float* __restrict__ sflat, const float* __restrict__ red,
                            float* __restrict__ out) {
    int i = blockIdx.x * blockDim.x + threadIdx.x;
    if (i < NT) out[OFF_SOFT + i] = expf(sflat[i] - red[0]) / red[1];
}

// wave-per-output-row gather: feature[row] * tanh(sflat[row])
__global__ void k_gather(const float* __restrict__ f, const int* __restrict__ permI,
                         const int* __restrict__ pcomI, const float* __restrict__ sflat,
                         float* __restrict__ out) {
    int j = blockIdx.x * 4 + (threadIdx.x >> 6);
    int lane = threadIdx.x & 63;
    int row = (j < 32768) ? permI[j] : pcomI[j - 32768];
    float tv = tanhf(sflat[row]);
    const float4* f4 = (const float4*)f;
    float4* o4 = (float4*)out;
    float4 v = f4[(size_t)row * 64 + lane];
    o4[(size_t)j * 64 + lane] = make_float4(v.x * tv, v.y * tv, v.z * tv, v.w * tv);
}

extern "C" void kernel_launch(void* const* d_in, const int* in_sizes, int n_in,
                              void* d_out, int out_size, void* d_ws, size_t ws_size,
                              hipStream_t stream) {
    const float* feature = (const float*)d_in[0];
    const int*   src     = (const int*)d_in[1];
    const int*   dst     = (const int*)d_in[2];
    const int*   label   = (const int*)d_in[3];
    const float* W       = (const float*)d_in[4];
    const float* b       = (const float*)d_in[5];
    const float* lw      = (const float*)d_in[6];
    const float* lb      = (const float*)d_in[7];
    float* out = (float*)d_out;
    char*  ws  = (char*)d_ws;

    float* sgcn    = (float*)(ws + WS_SGCN);
    float* h0      = (float*)(ws + WS_H0);
    float* sflat   = (float*)(ws + WS_SFLAT);
    float* gpart   = (float*)(ws + WS_GPART);
    float* c0      = (float*)(ws + WS_C0);
    float* c1      = (float*)(ws + WS_C1);
    float* red     = (float*)(ws + WS_RED);
    int*   permI   = (int*)(ws + WS_PERMI);
    int*   pcomI   = (int*)(ws + WS_PCOMI);

    k_pass1<<<512, 256, 0, stream>>>(feature, W, gpart, h0);
    k_centers<<<1, 256, 0, stream>>>(gpart, label, c0, c1);
    k_edges<<<Bg, 1024, 0, stream>>>(src, dst, h0, b, sgcn);
    k_score<<<NT / 4, 256, 0, stream>>>(feature, c0, c1, sgcn, label, lw, lb, sflat);
    k_topk<<<Bg, 1024, 0, stream>>>(sflat, permI, pcomI, out);
    k_softred<<<1, 1024, 0, stream>>>(sflat, red);
    k_softwrite<<<NT / 256, 256, 0, stream>>>(sflat, red, out);
    k_gather<<<NT / 4, 256, 0, stream>>>(feature, permI, pcomI, sflat, out);
}

// Round 3
// 227.478 us; speedup vs baseline: 1.4184x; 1.1362x over previous
//
#include <hip/hip_runtime.h>
#include <math.h>

#define Bg   64
#define Nn   1024
#define Dd   256
#define Ee   (Bg * Nn * 16)      // 1048576 edges
#define EPG  16384               // edges per graph
#define NT   (Bg * Nn)           // 65536 nodes
#define Kk   512

// d_out float offsets
#define OFF_DIS   0
#define OFF_COM   8388608
#define OFF_PERM  16777216
#define OFF_PCOM  16809984
#define OFF_SOFT  16842752

// ws byte offsets
#define WS_SGCN    0                       // NT floats: finished score_gcn
#define WS_H0      (NT * 4)
#define WS_SFLAT   (NT * 4 * 2)
#define WS_GPART   (NT * 4 * 3)            // 512 blocks * 256 floats
#define WS_C0      (WS_GPART + 512 * 256 * 4)
#define WS_C1      (WS_C0 + 1024)
#define WS_REDM    (WS_C1 + 1024)          // 64 floats: per-graph max
#define WS_REDS    (WS_REDM + 256)         // 64 floats: per-graph sumexp
#define WS_PERMI   (WS_REDS + 256)
#define WS_PCOMI   (WS_PERMI + 32768 * 4)

// 512 blocks x 256 threads; block = 128 rows. ONE feature read serves both
// the column partial sums (per-lane f4 accumulators -> LDS combine) and
// h0[row] = dot(feature[row], W) (wave-per-row shuffle reduce).
__global__ void k_pass1(const float* __restrict__ f, const float* __restrict__ W,
                        float* __restrict__ gpart, float* __restrict__ h0) {
    __shared__ float scol[4 * Dd];
    int blk  = blockIdx.x;
    int base = blk * 128;
    int t    = threadIdx.x;
    int lane = t & 63, wid = t >> 6;
    const float4* f4 = (const float4*)f;
    const float4* W4 = (const float4*)W;
    float4 w = W4[lane];
    float4 cs = make_float4(0.f, 0.f, 0.f, 0.f);
    for (int r = 0; r < 32; ++r) {
        int row = base + wid * 32 + r;
        float4 v = f4[(size_t)row * 64 + lane];
        cs.x += v.x; cs.y += v.y; cs.z += v.z; cs.w += v.w;
        float d = v.x * w.x + v.y * w.y + v.z * w.z + v.w * w.w;
        for (int o = 32; o > 0; o >>= 1) d += __shfl_xor(d, o);
        if (lane == 0) h0[row] = d;
    }
    ((float4*)scol)[wid * 64 + lane] = cs;
    __syncthreads();
    // t indexes a column 0..255
    float s = scol[t] + scol[Dd + t] + scol[2 * Dd + t] + scol[3 * Dd + t];
    gpart[blk * Dd + t] = s;
}

// 1 block x 256 threads: reduce partials -> gemb -> class centers (deterministic)
__global__ void k_centers(const float* __restrict__ gpart, const int* __restrict__ label,
                          float* __restrict__ c0, float* __restrict__ c1) {
    int t = threadIdx.x;
    int n1 = 0;
    for (int g = 0; g < Bg; ++g) n1 += label[g];
    float fn1 = fmaxf((float)n1, 1.f);
    float fn0 = fmaxf((float)(Bg - n1), 1.f);
    float s0 = 0.f, s1 = 0.f;
    for (int g = 0; g < Bg; ++g) {
        float v = 0.f;
        for (int p = 0; p < 8; ++p) v += gpart[(g * 8 + p) * Dd + t];
        v *= (1.f / (float)Nn);
        if (label[g]) s1 += v; else s0 += v;
    }
    c0[t] = s0 / fn0;
    c1[t] = s1 / fn1;
}

// One block per graph: degree count + normalized scatter, all in LDS.
__global__ __launch_bounds__(1024) void k_edges(
        const int* __restrict__ src, const int* __restrict__ dst,
        const float* __restrict__ h0, const float* __restrict__ b,
        float* __restrict__ sgcn) {
    __shared__ ushort2 eb[EPG];        // local (src,dst): 64 KB
    __shared__ int   sdo[Nn];
    __shared__ int   sdi[Nn];
    __shared__ float sagg[Nn];
    __shared__ float shn[Nn];
    int g = blockIdx.x, t = threadIdx.x;
    sdo[t] = 0; sdi[t] = 0; sagg[t] = 0.f;
    __syncthreads();
    int ebase = g * EPG;
    const int4* s4 = (const int4*)(src + ebase);
    const int4* d4 = (const int4*)(dst + ebase);
    #pragma unroll
    for (int i = t; i < EPG / 4; i += 1024) {
        int4 ss = s4[i];
        int4 dd = d4[i];
        int s0 = ss.x & (Nn - 1), s1 = ss.y & (Nn - 1), s2 = ss.z & (Nn - 1), s3 = ss.w & (Nn - 1);
        int e0 = dd.x & (Nn - 1), e1 = dd.y & (Nn - 1), e2 = dd.z & (Nn - 1), e3 = dd.w & (Nn - 1);
        eb[i * 4 + 0] = make_ushort2((unsigned short)s0, (unsigned short)e0);
        eb[i * 4 + 1] = make_ushort2((unsigned short)s1, (unsigned short)e1);
        eb[i * 4 + 2] = make_ushort2((unsigned short)s2, (unsigned short)e2);
        eb[i * 4 + 3] = make_ushort2((unsigned short)s3, (unsigned short)e3);
        atomicAdd(&sdo[s0], 1); atomicAdd(&sdo[s1], 1);
        atomicAdd(&sdo[s2], 1); atomicAdd(&sdo[s3], 1);
        atomicAdd(&sdi[e0], 1); atomicAdd(&sdi[e1], 1);
        atomicAdd(&sdi[e2], 1); atomicAdd(&sdi[e3], 1);
    }
    __syncthreads();
    {
        int dg = sdo[t]; if (dg < 1) dg = 1;
        shn[t] = h0[g * Nn + t] / sqrtf((float)dg);
    }
    __syncthreads();
    #pragma unroll
    for (int i = t; i < EPG; i += 1024) {
        ushort2 e = eb[i];
        atomicAdd(&sagg[e.y], shn[e.x]);
    }
    __syncthreads();
    {
        int dg = sdi[t]; if (dg < 1) dg = 1;
        float nd = 1.f / sqrtf((float)dg);
        sgcn[g * Nn + t] = sagg[t] * nd + b[0];
    }
}

// wave-per-node: distances to centers + combine scores
__global__ void k_score(const float* __restrict__ f, const float* __restrict__ c0,
                        const float* __restrict__ c1, const float* __restrict__ sgcn,
                        const int* __restrict__ label, const float* __restrict__ lw,
                        const float* __restrict__ lb, float* __restrict__ sflat) {
    int node = blockIdx.x * 4 + (threadIdx.x >> 6);
    int lane = threadIdx.x & 63;
    const float4* f4  = (const float4*)f;
    const float4* c04 = (const float4*)c0;
    const float4* c14 = (const float4*)c1;
    float4 v = f4[(size_t)node * 64 + lane];
    float4 a = c04[lane];
    float4 bb = c14[lane];
    float dx, acc0, acc1;
    dx = v.x - a.x;  acc0  = dx * dx;
    dx = v.y - a.y;  acc0 += dx * dx;
    dx = v.z - a.z;  acc0 += dx * dx;
    dx = v.w - a.w;  acc0 += dx * dx;
    dx = v.x - bb.x; acc1  = dx * dx;
    dx = v.y - bb.y; acc1 += dx * dx;
    dx = v.z - bb.z; acc1 += dx * dx;
    dx = v.w - bb.w; acc1 += dx * dx;
    for (int o = 32; o > 0; o >>= 1) {
        acc0 += __shfl_xor(acc0, o);
        acc1 += __shfl_xor(acc1, o);
    }
    if (lane == 0) {
        float d0 = sqrtf(acc0), d1 = sqrtf(acc1);
        int g = node >> 10;
        float sgn = label[g] ? 1.f : -1.f;
        float sdist = (d0 - d1) * sgn;
        sflat[node] = sgcn[node] * lw[0] + sdist * lw[1] + lb[0];
    }
}

// one block (1024 threads) per graph: packed-uint64 bitonic sort (desc value,
// asc index tiebreak), perm + complement (wave-shuffle scan), and per-graph
// softmax partials (max, sum exp).
__global__ __launch_bounds__(1024) void k_topk(
        const float* __restrict__ sflat, int* __restrict__ permI,
        int* __restrict__ pcomI, float* __restrict__ out,
        float* __restrict__ redM, float* __restrict__ redS) {
    __shared__ unsigned long long sk[1024];
    __shared__ int   sflag[1024];
    __shared__ int   swave[16];
    __shared__ float sred[32];
    int g = blockIdx.x, t = threadIdx.x;
    int lane = t & 63, w = t >> 6;
    float v = sflat[g * Nn + t];
    unsigned u = __float_as_uint(v);
    unsigned ord = u ^ ((u >> 31) ? 0xFFFFFFFFu : 0x80000000u);  // ascending uint == ascending float
    sk[t] = ((unsigned long long)ord << 32) | (unsigned)(1023 - t);
    __syncthreads();
    for (int k = 2; k <= 1024; k <<= 1) {
        for (int j = k >> 1; j > 0; j >>= 1) {
            int ixj = t ^ j;
            if (ixj > t) {
                unsigned long long a = sk[t], bk = sk[ixj];
                bool up = ((t & k) == 0);
                if ((a < bk) == up) { sk[t] = bk; sk[ixj] = a; }  // descending
            }
            __syncthreads();
        }
    }
    sflag[t] = 1;
    __syncthreads();
    if (t < Kk) {
        int loc = 1023 - (int)(sk[t] & 0xFFFFFFFFu);
        sflag[loc] = 0;
        int gi = g * Nn + loc;
        permI[g * Kk + t] = gi;
        out[OFF_PERM + g * Kk + t] = (float)gi;
    }
    __syncthreads();
    // wave-shuffle inclusive scan of flags
    int x = sflag[t];
    int inc = x;
    for (int o = 1; o < 64; o <<= 1) {
        int y = __shfl_up(inc, o);
        if (lane >= o) inc += y;
    }
    if (lane == 63) swave[w] = inc;
    __syncthreads();
    if (t < 16) {
        int a = swave[t];
        for (int o = 1; o < 16; o <<= 1) {
            int y = __shfl_up(a, o);
            if (t >= o) a += y;
        }
        swave[t] = a;
    }
    __syncthreads();
    int basep = (w > 0) ? swave[w - 1] : 0;
    if (x) {
        int pos = basep + inc - 1;
        int gi = g * Nn + t;
        pcomI[g * Kk + pos] = gi;
        out[OFF_PCOM + g * Kk + pos] = (float)gi;
    }
    // softmax partials for this graph
    float m = v;
    for (int o = 32; o > 0; o >>= 1) m = fmaxf(m, __shfl_xor(m, o));
    if (lane == 0) sred[w] = m;
    __syncthreads();
    if (t < 16) {
        float a = sred[t];
        for (int o = 8; o > 0; o >>= 1) a = fmaxf(a, __shfl_xor(a, o));
        if (t == 0) sred[0] = a;
    }
    __syncthreads();
    m = sred[0];
    float s = expf(v - m);
    for (int o = 32; o > 0; o >>= 1) s += __shfl_xor(s, o);
    if (lane == 0) sred[16 + w] = s;
    __syncthreads();
    if (t < 16) {
        float a = sred[16 + t];
        for (int o = 8; o > 0; o >>= 1) a += __shfl_xor(a, o);
        if (t == 0) { redM[g] = m; redS[g] = a; }
    }
}

// gather rows * tanh + softmax write; 64-pair softmax combine done per block.
__global__ void k_write(const float* __restrict__ f, const int* __restrict__ permI,
                        const int* __restrict__ pcomI, const float* __restrict__ sflat,
                        const float* __restrict__ redM, const float* __restrict__ redS,
                        float* __restrict__ out) {
    __shared__ float sMS[2];
    int t = threadIdx.x;
    if (t < 64) {
        float m = redM[t];
        float mm = m;
        for (int o = 32; o > 0; o >>= 1) mm = fmaxf(mm, __shfl_xor(mm, o));
        float s = redS[t] * expf(m - mm);
        for (int o = 32; o > 0; o >>= 1) s += __shfl_xor(s, o);
        if (t == 0) { sMS[0] = mm; sMS[1] = s; }
    }
    __syncthreads();
    float M = sMS[0], S = sMS[1];
    if (t < 4) {
        int i = blockIdx.x * 4 + t;
        out[OFF_SOFT + i] = expf(sflat[i] - M) / S;
    }
    int j = blockIdx.x * 4 + (t >> 6);
    int lane = t & 63;
    int row = (j < 32768) ? permI[j] : pcomI[j - 32768];
    float tv = tanhf(sflat[row]);
    const float4* f4 = (const float4*)f;
    float4* o4 = (float4*)out;
    float4 v = f4[(size_t)row * 64 + lane];
    o4[(size_t)j * 64 + lane] = make_float4(v.x * tv, v.y * tv, v.z * tv, v.w * tv);
}

extern "C" void kernel_launch(void* const* d_in, const int* in_sizes, int n_in,
                              void* d_out, int out_size, void* d_ws, size_t ws_size,
                              hipStream_t stream) {
    const float* feature = (const float*)d_in[0];
    const int*   src     = (const int*)d_in[1];
    const int*   dst     = (const int*)d_in[2];
    const int*   label   = (const int*)d_in[3];
    const float* W       = (const float*)d_in[4];
    const float* b       = (const float*)d_in[5];
    const float* lw      = (const float*)d_in[6];
    const float* lb      = (const float*)d_in[7];
    float* out = (float*)d_out;
    char*  ws  = (char*)d_ws;

    float* sgcn    = (float*)(ws + WS_SGCN);
    float* h0      = (float*)(ws + WS_H0);
    float* sflat   = (float*)(ws + WS_SFLAT);
    float* gpart   = (float*)(ws + WS_GPART);
    float* c0      = (float*)(ws + WS_C0);
    float* c1      = (float*)(ws + WS_C1);
    float* redM    = (float*)(ws + WS_REDM);
    float* redS    = (float*)(ws + WS_REDS);
    int*   permI   = (int*)(ws + WS_PERMI);
    int*   pcomI   = (int*)(ws + WS_PCOMI);

    k_pass1<<<512, 256, 0, stream>>>(feature, W, gpart, h0);
    k_edges<<<Bg, 1024, 0, stream>>>(src, dst, h0, b, sgcn);
    k_centers<<<1, 256, 0, stream>>>(gpart, label, c0, c1);
    k_score<<<NT / 4, 256, 0, stream>>>(feature, c0, c1, sgcn, label, lw, lb, sflat);
    k_topk<<<Bg, 1024, 0, stream>>>(sflat, permI, pcomI, out, redM, redS);
    k_write<<<NT / 4, 256, 0, stream>>>(feature, permI, pcomI, sflat, redM, redS, out);
}

// Round 4
// 223.862 us; speedup vs baseline: 1.4413x; 1.0162x over previous
//
#include <hip/hip_runtime.h>
#include <math.h>

#define Bg   64
#define Nn   1024
#define Dd   256
#define Ee   (Bg * Nn * 16)      // 1048576 edges
#define EPG  16384               // edges per graph
#define NT   (Bg * Nn)           // 65536 nodes
#define Kk   512

// d_out float offsets
#define OFF_DIS   0
#define OFF_COM   8388608
#define OFF_PERM  16777216
#define OFF_PCOM  16809984
#define OFF_SOFT  16842752

// ws byte offsets
#define WS_SGCN    0                       // NT floats: finished score_gcn
#define WS_H0      (NT * 4)
#define WS_SFLAT   (NT * 4 * 2)
#define WS_GPART   (NT * 4 * 3)            // 512 blocks * 256 floats
#define WS_C0      (WS_GPART + 512 * 256 * 4)
#define WS_C1      (WS_C0 + 1024)
#define WS_REDM    (WS_C1 + 1024)          // 64 floats: per-graph max
#define WS_REDS    (WS_REDM + 256)         // 64 floats: per-graph sumexp
#define WS_PERMI   (WS_REDS + 256)
#define WS_PCOMI   (WS_PERMI + 32768 * 4)

// 512 blocks x 256 threads; block = 128 rows. ONE feature read serves both
// the column partial sums and h0[row] = dot(feature[row], W).
__global__ void k_pass1(const float* __restrict__ f, const float* __restrict__ W,
                        float* __restrict__ gpart, float* __restrict__ h0) {
    __shared__ float scol[4 * Dd];
    int blk  = blockIdx.x;
    int base = blk * 128;
    int t    = threadIdx.x;
    int lane = t & 63, wid = t >> 6;
    const float4* f4 = (const float4*)f;
    const float4* W4 = (const float4*)W;
    float4 w = W4[lane];
    float4 cs = make_float4(0.f, 0.f, 0.f, 0.f);
    for (int r = 0; r < 32; ++r) {
        int row = base + wid * 32 + r;
        float4 v = f4[(size_t)row * 64 + lane];
        cs.x += v.x; cs.y += v.y; cs.z += v.z; cs.w += v.w;
        float d = v.x * w.x + v.y * w.y + v.z * w.z + v.w * w.w;
        for (int o = 32; o > 0; o >>= 1) d += __shfl_xor(d, o);
        if (lane == 0) h0[row] = d;
    }
    ((float4*)scol)[wid * 64 + lane] = cs;
    __syncthreads();
    float s = scol[t] + scol[Dd + t] + scol[2 * Dd + t] + scol[3 * Dd + t];
    gpart[blk * Dd + t] = s;
}

// One block per graph: degree count + normalized scatter, all in LDS.
// Block 0 additionally computes class centers (hidden behind other blocks).
__global__ __launch_bounds__(1024) void k_edges(
        const int* __restrict__ src, const int* __restrict__ dst,
        const float* __restrict__ h0, const float* __restrict__ b,
        const float* __restrict__ gpart, const int* __restrict__ label,
        float* __restrict__ sgcn, float* __restrict__ c0, float* __restrict__ c1) {
    __shared__ ushort2 eb[EPG];        // local (src,dst): 64 KB
    __shared__ int   sdo[Nn];
    __shared__ int   sdi[Nn];
    __shared__ float sagg[Nn];
    __shared__ float shn[Nn];
    int g = blockIdx.x, t = threadIdx.x;
    sdo[t] = 0; sdi[t] = 0; sagg[t] = 0.f;
    __syncthreads();
    int ebase = g * EPG;
    const int4* s4 = (const int4*)(src + ebase);
    const int4* d4 = (const int4*)(dst + ebase);
    #pragma unroll
    for (int i = t; i < EPG / 4; i += 1024) {
        int4 ss = s4[i];
        int4 dd = d4[i];
        int s0 = ss.x & (Nn - 1), s1 = ss.y & (Nn - 1), s2 = ss.z & (Nn - 1), s3 = ss.w & (Nn - 1);
        int e0 = dd.x & (Nn - 1), e1 = dd.y & (Nn - 1), e2 = dd.z & (Nn - 1), e3 = dd.w & (Nn - 1);
        eb[i * 4 + 0] = make_ushort2((unsigned short)s0, (unsigned short)e0);
        eb[i * 4 + 1] = make_ushort2((unsigned short)s1, (unsigned short)e1);
        eb[i * 4 + 2] = make_ushort2((unsigned short)s2, (unsigned short)e2);
        eb[i * 4 + 3] = make_ushort2((unsigned short)s3, (unsigned short)e3);
        atomicAdd(&sdo[s0], 1); atomicAdd(&sdo[s1], 1);
        atomicAdd(&sdo[s2], 1); atomicAdd(&sdo[s3], 1);
        atomicAdd(&sdi[e0], 1); atomicAdd(&sdi[e1], 1);
        atomicAdd(&sdi[e2], 1); atomicAdd(&sdi[e3], 1);
    }
    __syncthreads();
    {
        int dg = sdo[t]; if (dg < 1) dg = 1;
        shn[t] = h0[g * Nn + t] / sqrtf((float)dg);
    }
    __syncthreads();
    #pragma unroll
    for (int i = t; i < EPG; i += 1024) {
        ushort2 e = eb[i];
        atomicAdd(&sagg[e.y], shn[e.x]);
    }
    __syncthreads();
    {
        int dg = sdi[t]; if (dg < 1) dg = 1;
        float nd = 1.f / sqrtf((float)dg);
        sgcn[g * Nn + t] = sagg[t] * nd + b[0];
    }
    // centers (deterministic), block 0 only, threads 0..255 (one per column)
    if (g == 0 && t < Dd) {
        int n1 = 0;
        for (int gg = 0; gg < Bg; ++gg) n1 += label[gg];
        float fn1 = fmaxf((float)n1, 1.f);
        float fn0 = fmaxf((float)(Bg - n1), 1.f);
        float s0 = 0.f, s1 = 0.f;
        for (int gg = 0; gg < Bg; ++gg) {
            float v = 0.f;
            for (int p = 0; p < 8; ++p) v += gpart[(gg * 8 + p) * Dd + t];
            v *= (1.f / (float)Nn);
            if (label[gg]) s1 += v; else s0 += v;
        }
        c0[t] = s0 / fn0;
        c1[t] = s1 / fn1;
    }
}

// wave-per-node: distances to centers + combine scores
__global__ void k_score(const float* __restrict__ f, const float* __restrict__ c0,
                        const float* __restrict__ c1, const float* __restrict__ sgcn,
                        const int* __restrict__ label, const float* __restrict__ lw,
                        const float* __restrict__ lb, float* __restrict__ sflat) {
    int node = blockIdx.x * 4 + (threadIdx.x >> 6);
    int lane = threadIdx.x & 63;
    const float4* f4  = (const float4*)f;
    const float4* c04 = (const float4*)c0;
    const float4* c14 = (const float4*)c1;
    float4 v = f4[(size_t)node * 64 + lane];
    float4 a = c04[lane];
    float4 bb = c14[lane];
    float dx, acc0, acc1;
    dx = v.x - a.x;  acc0  = dx * dx;
    dx = v.y - a.y;  acc0 += dx * dx;
    dx = v.z - a.z;  acc0 += dx * dx;
    dx = v.w - a.w;  acc0 += dx * dx;
    dx = v.x - bb.x; acc1  = dx * dx;
    dx = v.y - bb.y; acc1 += dx * dx;
    dx = v.z - bb.z; acc1 += dx * dx;
    dx = v.w - bb.w; acc1 += dx * dx;
    for (int o = 32; o > 0; o >>= 1) {
        acc0 += __shfl_xor(acc0, o);
        acc1 += __shfl_xor(acc1, o);
    }
    if (lane == 0) {
        float d0 = sqrtf(acc0), d1 = sqrtf(acc1);
        int g = node >> 10;
        float sgn = label[g] ? 1.f : -1.f;
        float sdist = (d0 - d1) * sgn;
        sflat[node] = sgcn[node] * lw[0] + sdist * lw[1] + lb[0];
    }
}

// one block (512 threads) per graph: all-active bitonic sort of packed u64 keys
// (desc value, asc index tiebreak), perm + complement + softmax partials.
__global__ __launch_bounds__(512) void k_topk(
        const float* __restrict__ sflat, int* __restrict__ permI,
        int* __restrict__ pcomI, float* __restrict__ out,
        float* __restrict__ redM, float* __restrict__ redS) {
    __shared__ unsigned long long sk[1024];
    __shared__ int   sflag[1024];
    __shared__ int   swave[8];
    __shared__ float sred[16];
    int g = blockIdx.x, t = threadIdx.x;
    int lane = t & 63, w = t >> 6;
    float v0 = sflat[g * Nn + t];
    float v1 = sflat[g * Nn + t + 512];
    unsigned u0 = __float_as_uint(v0);
    unsigned u1 = __float_as_uint(v1);
    unsigned o0 = u0 ^ ((u0 >> 31) ? 0xFFFFFFFFu : 0x80000000u);
    unsigned o1 = u1 ^ ((u1 >> 31) ? 0xFFFFFFFFu : 0x80000000u);
    sk[t]       = ((unsigned long long)o0 << 32) | (unsigned)(1023 - t);
    sk[t + 512] = ((unsigned long long)o1 << 32) | (unsigned)(1023 - (t + 512));
    __syncthreads();
    // all-active bitonic: thread t handles pair (l, l+j)
    for (int k = 2; k <= 1024; k <<= 1) {
        for (int j = k >> 1; j > 0; j >>= 1) {
            int l = ((t & ~(j - 1)) << 1) | (t & (j - 1));
            int r = l | j;
            unsigned long long a = sk[l], bk = sk[r];
            bool up = ((l & k) == 0);
            if ((a < bk) == up) { sk[l] = bk; sk[r] = a; }   // descending when up
            __syncthreads();
        }
    }
    sflag[t] = 1; sflag[t + 512] = 1;
    __syncthreads();
    {
        // top-512 = sk[0..511], exactly one per thread
        int loc = 1023 - (int)(sk[t] & 0xFFFFFFFFu);
        sflag[loc] = 0;
        int gi = g * Nn + loc;
        permI[g * Kk + t] = gi;
        out[OFF_PERM + g * Kk + t] = (float)gi;
    }
    __syncthreads();
    // pairwise scan: thread t owns elements 2t, 2t+1 (index order preserved)
    int f0 = sflag[2 * t], f1 = sflag[2 * t + 1];
    int f2 = f0 + f1;
    int inc = f2;
    for (int o = 1; o < 64; o <<= 1) {
        int y = __shfl_up(inc, o);
        if (lane >= o) inc += y;
    }
    if (lane == 63) swave[w] = inc;
    __syncthreads();
    if (t < 8) {
        int a = swave[t];
        for (int o = 1; o < 8; o <<= 1) {
            int y = __shfl_up(a, o);
            if (t >= o) a += y;
        }
        swave[t] = a;
    }
    __syncthreads();
    int basep = ((w > 0) ? swave[w - 1] : 0) + (inc - f2);   // exclusive before 2t
    if (f0) {
        int gi = g * Nn + 2 * t;
        pcomI[g * Kk + basep] = gi;
        out[OFF_PCOM + g * Kk + basep] = (float)gi;
    }
    if (f1) {
        int pos = basep + f0;
        int gi = g * Nn + 2 * t + 1;
        pcomI[g * Kk + pos] = gi;
        out[OFF_PCOM + g * Kk + pos] = (float)gi;
    }
    // softmax partials for this graph (over original values; order-agnostic)
    float m = fmaxf(v0, v1);
    for (int o = 32; o > 0; o >>= 1) m = fmaxf(m, __shfl_xor(m, o));
    if (lane == 0) sred[w] = m;
    __syncthreads();
    if (t < 8) {
        float a = sred[t];
        for (int o = 4; o > 0; o >>= 1) a = fmaxf(a, __shfl_xor(a, o));
        if (t == 0) sred[0] = a;
    }
    __syncthreads();
    m = sred[0];
    float s = expf(v0 - m) + expf(v1 - m);
    for (int o = 32; o > 0; o >>= 1) s += __shfl_xor(s, o);
    if (lane == 0) sred[8 + w] = s;
    __syncthreads();
    if (t < 8) {
        float a = sred[8 + t];
        for (int o = 4; o > 0; o >>= 1) a += __shfl_xor(a, o);
        if (t == 0) { redM[g] = m; redS[g] = a; }
    }
}

// gather rows * tanh + softmax write; 64-pair softmax combine per block.
__global__ void k_write(const float* __restrict__ f, const int* __restrict__ permI,
                        const int* __restrict__ pcomI, const float* __restrict__ sflat,
                        const float* __restrict__ redM, const float* __restrict__ redS,
                        float* __restrict__ out) {
    __shared__ float sMS[2];
    int t = threadIdx.x;
    if (t < 64) {
        float m = redM[t];
        float mm = m;
        for (int o = 32; o > 0; o >>= 1) mm = fmaxf(mm, __shfl_xor(mm, o));
        float s = redS[t] * expf(m - mm);
        for (int o = 32; o > 0; o >>= 1) s += __shfl_xor(s, o);
        if (t == 0) { sMS[0] = mm; sMS[1] = s; }
    }
    __syncthreads();
    float M = sMS[0], S = sMS[1];
    if (t < 4) {
        int i = blockIdx.x * 4 + t;
        out[OFF_SOFT + i] = expf(sflat[i] - M) / S;
    }
    int j = blockIdx.x * 4 + (t >> 6);
    int lane = t & 63;
    int row = (j < 32768) ? permI[j] : pcomI[j - 32768];
    float tv = tanhf(sflat[row]);
    const float4* f4 = (const float4*)f;
    float4* o4 = (float4*)out;
    float4 v = f4[(size_t)row * 64 + lane];
    o4[(size_t)j * 64 + lane] = make_float4(v.x * tv, v.y * tv, v.z * tv, v.w * tv);
}

extern "C" void kernel_launch(void* const* d_in, const int* in_sizes, int n_in,
                              void* d_out, int out_size, void* d_ws, size_t ws_size,
                              hipStream_t stream) {
    const float* feature = (const float*)d_in[0];
    const int*   src     = (const int*)d_in[1];
    const int*   dst     = (const int*)d_in[2];
    const int*   label   = (const int*)d_in[3];
    const float* W       = (const float*)d_in[4];
    const float* b       = (const float*)d_in[5];
    const float* lw      = (const float*)d_in[6];
    const float* lb      = (const float*)d_in[7];
    float* out = (float*)d_out;
    char*  ws  = (char*)d_ws;

    float* sgcn    = (float*)(ws + WS_SGCN);
    float* h0      = (float*)(ws + WS_H0);
    float* sflat   = (float*)(ws + WS_SFLAT);
    float* gpart   = (float*)(ws + WS_GPART);
    float* c0      = (float*)(ws + WS_C0);
    float* c1      = (float*)(ws + WS_C1);
    float* redM    = (float*)(ws + WS_REDM);
    float* redS    = (float*)(ws + WS_REDS);
    int*   permI   = (int*)(ws + WS_PERMI);
    int*   pcomI   = (int*)(ws + WS_PCOMI);

    k_pass1<<<512, 256, 0, stream>>>(feature, W, gpart, h0);
    k_edges<<<Bg, 1024, 0, stream>>>(src, dst, h0, b, gpart, label, sgcn, c0, c1);
    k_score<<<NT / 4, 256, 0, stream>>>(feature, c0, c1, sgcn, label, lw, lb, sflat);
    k_topk<<<Bg, 512, 0, stream>>>(sflat, permI, pcomI, out, redM, redS);
    k_write<<<NT / 4, 256, 0, stream>>>(feature, permI, pcomI, sflat, redM, redS, out);
}

// Round 5
// 210.951 us; speedup vs baseline: 1.5295x; 1.0612x over previous
//
#include <hip/hip_runtime.h>
#include <math.h>

#define Bg   64
#define Nn   1024
#define Dd   256
#define Ee   (Bg * Nn * 16)      // 1048576 edges
#define EPG  16384               // edges per graph
#define EPB  4096                // edges per edge-slice block (4 slices/graph)
#define NT   (Bg * Nn)           // 65536 nodes
#define Kk   512

// d_out float offsets
#define OFF_DIS   0
#define OFF_COM   8388608
#define OFF_PERM  16777216
#define OFF_PCOM  16809984
#define OFF_SOFT  16842752

// ws byte offsets (ws is ~200 MB; we use ~8.5 MB)
#define WS_H0      0
#define WS_SFLAT   (NT * 4)
#define WS_GPART   (NT * 4 * 2)                 // 512 blocks * 256 floats
#define WS_C0      (WS_GPART + 512 * 256 * 4)
#define WS_C1      (WS_C0 + 1024)
#define WS_REDM    (WS_C1 + 1024)               // 64 floats
#define WS_REDS    (WS_REDM + 256)              // 64 floats
#define WS_PERMI   (WS_REDS + 256)
#define WS_PCOMI   (WS_PERMI + 32768 * 4)
#define WS_EPACK   (WS_PCOMI + 32768 * 4)       // Ee uints (packed src|dst<<16): 4 MB
#define WS_DO4     (WS_EPACK + Ee * 4)          // 4 slice-partials of deg_out: 1 MB
#define WS_DI4     (WS_DO4 + 4 * NT * 4)        // 4 slice-partials of deg_in : 1 MB
#define WS_AGG4    (WS_DI4 + 4 * NT * 4)        // 4 slice-partials of agg    : 1 MB

// 768 blocks x 256 threads.
// Blocks 0..511: fused column-sums + h0 = feature @ W  (one feature read).
// Blocks 512..767: edge slice pass A — LDS degree count -> slice partials,
//                  plus packed-edge staging for pass B.
__global__ __launch_bounds__(256) void k_mix(
        const float* __restrict__ f, const float* __restrict__ W,
        const int* __restrict__ src, const int* __restrict__ dst,
        float* __restrict__ gpart, float* __restrict__ h0,
        unsigned* __restrict__ epack, int* __restrict__ do4, int* __restrict__ di4) {
    __shared__ int smem[2048];                  // 8 KB union
    int blk = blockIdx.x;
    int t   = threadIdx.x;
    if (blk < 512) {
        float* scol = (float*)smem;             // 4*256 floats
        int base = blk * 128;
        int lane = t & 63, wid = t >> 6;
        const float4* f4 = (const float4*)f;
        const float4* W4 = (const float4*)W;
        float4 w = W4[lane];
        float4 cs = make_float4(0.f, 0.f, 0.f, 0.f);
        for (int r = 0; r < 32; ++r) {
            int row = base + wid * 32 + r;
            float4 v = f4[(size_t)row * 64 + lane];
            cs.x += v.x; cs.y += v.y; cs.z += v.z; cs.w += v.w;
            float d = v.x * w.x + v.y * w.y + v.z * w.z + v.w * w.w;
            for (int o = 32; o > 0; o >>= 1) d += __shfl_xor(d, o);
            if (lane == 0) h0[row] = d;
        }
        ((float4*)scol)[wid * 64 + lane] = cs;
        __syncthreads();
        float s = scol[t] + scol[Dd + t] + scol[2 * Dd + t] + scol[3 * Dd + t];
        gpart[blk * Dd + t] = s;
    } else {
        int* sdo = smem;                        // [1024]
        int* sdi = smem + 1024;                 // [1024]
        int blk2 = blk - 512;
        int g = blk2 >> 2, sl = blk2 & 3;
        #pragma unroll
        for (int j = 0; j < 4; ++j) { sdo[t + j * 256] = 0; sdi[t + j * 256] = 0; }
        __syncthreads();
        int ebase = g * EPG + sl * EPB;
        const int4* s4 = (const int4*)(src + ebase);
        const int4* d4 = (const int4*)(dst + ebase);
        uint4* p4 = (uint4*)(epack + ebase);
        #pragma unroll
        for (int i = t; i < EPB / 4; i += 256) {
            int4 ss = s4[i];
            int4 dd = d4[i];
            int s0 = ss.x & (Nn - 1), s1 = ss.y & (Nn - 1), s2 = ss.z & (Nn - 1), s3 = ss.w & (Nn - 1);
            int e0 = dd.x & (Nn - 1), e1 = dd.y & (Nn - 1), e2 = dd.z & (Nn - 1), e3 = dd.w & (Nn - 1);
            uint4 pk;
            pk.x = (unsigned)(s0 | (e0 << 16));
            pk.y = (unsigned)(s1 | (e1 << 16));
            pk.z = (unsigned)(s2 | (e2 << 16));
            pk.w = (unsigned)(s3 | (e3 << 16));
            p4[i] = pk;
            atomicAdd(&sdo[s0], 1); atomicAdd(&sdo[s1], 1);
            atomicAdd(&sdo[s2], 1); atomicAdd(&sdo[s3], 1);
            atomicAdd(&sdi[e0], 1); atomicAdd(&sdi[e1], 1);
            atomicAdd(&sdi[e2], 1); atomicAdd(&sdi[e3], 1);
        }
        __syncthreads();
        int base = sl * NT + g * Nn;
        #pragma unroll
        for (int j = 0; j < 4; ++j) {
            do4[base + t + j * 256] = sdo[t + j * 256];
            di4[base + t + j * 256] = sdi[t + j * 256];
        }
    }
}

// 256 blocks x 1024 threads: edge pass B — normalized scatter into LDS,
// store per-slice agg partial. Block 0 also computes class centers.
__global__ __launch_bounds__(1024) void k_edgeB(
        const unsigned* __restrict__ epack, const float* __restrict__ h0,
        const int* __restrict__ do4, const float* __restrict__ gpart,
        const int* __restrict__ label, float* __restrict__ agg4,
        float* __restrict__ c0, float* __restrict__ c1) {
    __shared__ float shn[Nn];
    __shared__ float sagg[Nn];
    int blk = blockIdx.x, t = threadIdx.x;
    int g = blk >> 2, sl = blk & 3;
    {
        int idx = g * Nn + t;
        int dg = do4[idx] + do4[NT + idx] + do4[2 * NT + idx] + do4[3 * NT + idx];
        if (dg < 1) dg = 1;
        shn[t] = h0[idx] / sqrtf((float)dg);
        sagg[t] = 0.f;
    }
    __syncthreads();
    {
        const uint4* p4 = (const uint4*)(epack + g * EPG + sl * EPB);
        uint4 pk = p4[t];                      // 1024 threads x 4 edges = 4096
        atomicAdd(&sagg[pk.x >> 16], shn[pk.x & 0xFFFF]);
        atomicAdd(&sagg[pk.y >> 16], shn[pk.y & 0xFFFF]);
        atomicAdd(&sagg[pk.z >> 16], shn[pk.z & 0xFFFF]);
        atomicAdd(&sagg[pk.w >> 16], shn[pk.w & 0xFFFF]);
    }
    __syncthreads();
    agg4[sl * NT + g * Nn + t] = sagg[t];
    // centers (deterministic), block 0, threads 0..255 (one per column)
    if (blk == 0 && t < Dd) {
        int n1 = 0;
        for (int gg = 0; gg < Bg; ++gg) n1 += label[gg];
        float fn1 = fmaxf((float)n1, 1.f);
        float fn0 = fmaxf((float)(Bg - n1), 1.f);
        float s0 = 0.f, s1 = 0.f;
        for (int gg = 0; gg < Bg; ++gg) {
            float v = 0.f;
            for (int p = 0; p < 8; ++p) v += gpart[(gg * 8 + p) * Dd + t];
            v *= (1.f / (float)Nn);
            if (label[gg]) s1 += v; else s0 += v;
        }
        c0[t] = s0 / fn0;
        c1[t] = s1 / fn1;
    }
}

// wave-per-node: distances to centers + finalize sgcn + combine scores
__global__ void k_score(const float* __restrict__ f, const float* __restrict__ c0,
                        const float* __restrict__ c1, const float* __restrict__ agg4,
                        const int* __restrict__ di4, const int* __restrict__ label,
                        const float* __restrict__ b, const float* __restrict__ lw,
                        const float* __restrict__ lb, float* __restrict__ sflat) {
    int node = blockIdx.x * 4 + (threadIdx.x >> 6);
    int lane = threadIdx.x & 63;
    const float4* f4  = (const float4*)f;
    const float4* c04 = (const float4*)c0;
    const float4* c14 = (const float4*)c1;
    float4 v = f4[(size_t)node * 64 + lane];
    float4 a = c04[lane];
    float4 bb = c14[lane];
    float dx, acc0, acc1;
    dx = v.x - a.x;  acc0  = dx * dx;
    dx = v.y - a.y;  acc0 += dx * dx;
    dx = v.z - a.z;  acc0 += dx * dx;
    dx = v.w - a.w;  acc0 += dx * dx;
    dx = v.x - bb.x; acc1  = dx * dx;
    dx = v.y - bb.y; acc1 += dx * dx;
    dx = v.z - bb.z; acc1 += dx * dx;
    dx = v.w - bb.w; acc1 += dx * dx;
    for (int o = 32; o > 0; o >>= 1) {
        acc0 += __shfl_xor(acc0, o);
        acc1 += __shfl_xor(acc1, o);
    }
    if (lane == 0) {
        float d0 = sqrtf(acc0), d1 = sqrtf(acc1);
        int g = node >> 10;
        float sgn = label[g] ? 1.f : -1.f;
        float sdist = (d0 - d1) * sgn;
        float agg = agg4[node] + agg4[NT + node] + agg4[2 * NT + node] + agg4[3 * NT + node];
        int dg = di4[node] + di4[NT + node] + di4[2 * NT + node] + di4[3 * NT + node];
        if (dg < 1) dg = 1;
        float sgcn = agg / sqrtf((float)dg) + b[0];
        sflat[node] = sgcn * lw[0] + sdist * lw[1] + lb[0];
    }
}

// one block (512 threads) per graph: all-active bitonic sort of packed u64 keys
// (desc value, asc index tiebreak), perm + complement + softmax partials.
__global__ __launch_bounds__(512) void k_topk(
        const float* __restrict__ sflat, int* __restrict__ permI,
        int* __restrict__ pcomI, float* __restrict__ out,
        float* __restrict__ redM, float* __restrict__ redS) {
    __shared__ unsigned long long sk[1024];
    __shared__ int   sflag[1024];
    __shared__ int   swave[8];
    __shared__ float sred[16];
    int g = blockIdx.x, t = threadIdx.x;
    int lane = t & 63, w = t >> 6;
    float v0 = sflat[g * Nn + t];
    float v1 = sflat[g * Nn + t + 512];
    unsigned u0 = __float_as_uint(v0);
    unsigned u1 = __float_as_uint(v1);
    unsigned o0 = u0 ^ ((u0 >> 31) ? 0xFFFFFFFFu : 0x80000000u);
    unsigned o1 = u1 ^ ((u1 >> 31) ? 0xFFFFFFFFu : 0x80000000u);
    sk[t]       = ((unsigned long long)o0 << 32) | (unsigned)(1023 - t);
    sk[t + 512] = ((unsigned long long)o1 << 32) | (unsigned)(1023 - (t + 512));
    __syncthreads();
    for (int k = 2; k <= 1024; k <<= 1) {
        for (int j = k >> 1; j > 0; j >>= 1) {
            int l = ((t & ~(j - 1)) << 1) | (t & (j - 1));
            int r = l | j;
            unsigned long long a = sk[l], bk = sk[r];
            bool up = ((l & k) == 0);
            if ((a < bk) == up) { sk[l] = bk; sk[r] = a; }
            __syncthreads();
        }
    }
    sflag[t] = 1; sflag[t + 512] = 1;
    __syncthreads();
    {
        int loc = 1023 - (int)(sk[t] & 0xFFFFFFFFu);
        sflag[loc] = 0;
        int gi = g * Nn + loc;
        permI[g * Kk + t] = gi;
        out[OFF_PERM + g * Kk + t] = (float)gi;
    }
    __syncthreads();
    int f0 = sflag[2 * t], f1 = sflag[2 * t + 1];
    int f2 = f0 + f1;
    int inc = f2;
    for (int o = 1; o < 64; o <<= 1) {
        int y = __shfl_up(inc, o);
        if (lane >= o) inc += y;
    }
    if (lane == 63) swave[w] = inc;
    __syncthreads();
    if (t < 8) {
        int a = swave[t];
        for (int o = 1; o < 8; o <<= 1) {
            int y = __shfl_up(a, o);
            if (t >= o) a += y;
        }
        swave[t] = a;
    }
    __syncthreads();
    int basep = ((w > 0) ? swave[w - 1] : 0) + (inc - f2);
    if (f0) {
        int gi = g * Nn + 2 * t;
        pcomI[g * Kk + basep] = gi;
        out[OFF_PCOM + g * Kk + basep] = (float)gi;
    }
    if (f1) {
        int pos = basep + f0;
        int gi = g * Nn + 2 * t + 1;
        pcomI[g * Kk + pos] = gi;
        out[OFF_PCOM + g * Kk + pos] = (float)gi;
    }
    float m = fmaxf(v0, v1);
    for (int o = 32; o > 0; o >>= 1) m = fmaxf(m, __shfl_xor(m, o));
    if (lane == 0) sred[w] = m;
    __syncthreads();
    if (t < 8) {
        float a = sred[t];
        for (int o = 4; o > 0; o >>= 1) a = fmaxf(a, __shfl_xor(a, o));
        if (t == 0) sred[0] = a;
    }
    __syncthreads();
    m = sred[0];
    float s = expf(v0 - m) + expf(v1 - m);
    for (int o = 32; o > 0; o >>= 1) s += __shfl_xor(s, o);
    if (lane == 0) sred[8 + w] = s;
    __syncthreads();
    if (t < 8) {
        float a = sred[8 + t];
        for (int o = 4; o > 0; o >>= 1) a += __shfl_xor(a, o);
        if (t == 0) { redM[g] = m; redS[g] = a; }
    }
}

// gather rows * tanh + softmax write; 64-pair softmax combine per block.
__global__ void k_write(const float* __restrict__ f, const int* __restrict__ permI,
                        const int* __restrict__ pcomI, const float* __restrict__ sflat,
                        const float* __restrict__ redM, const float* __restrict__ redS,
                        float* __restrict__ out) {
    __shared__ float sMS[2];
    int t = threadIdx.x;
    if (t < 64) {
        float m = redM[t];
        float mm = m;
        for (int o = 32; o > 0; o >>= 1) mm = fmaxf(mm, __shfl_xor(mm, o));
        float s = redS[t] * expf(m - mm);
        for (int o = 32; o > 0; o >>= 1) s += __shfl_xor(s, o);
        if (t == 0) { sMS[0] = mm; sMS[1] = s; }
    }
    __syncthreads();
    float M = sMS[0], S = sMS[1];
    if (t < 4) {
        int i = blockIdx.x * 4 + t;
        out[OFF_SOFT + i] = expf(sflat[i] - M) / S;
    }
    int j = blockIdx.x * 4 + (t >> 6);
    int lane = t & 63;
    int row = (j < 32768) ? permI[j] : pcomI[j - 32768];
    float tv = tanhf(sflat[row]);
    const float4* f4 = (const float4*)f;
    float4* o4 = (float4*)out;
    float4 v = f4[(size_t)row * 64 + lane];
    o4[(size_t)j * 64 + lane] = make_float4(v.x * tv, v.y * tv, v.z * tv, v.w * tv);
}

extern "C" void kernel_launch(void* const* d_in, const int* in_sizes, int n_in,
                              void* d_out, int out_size, void* d_ws, size_t ws_size,
                              hipStream_t stream) {
    const float* feature = (const float*)d_in[0];
    const int*   src     = (const int*)d_in[1];
    const int*   dst     = (const int*)d_in[2];
    const int*   label   = (const int*)d_in[3];
    const float* W       = (const float*)d_in[4];
    const float* b       = (const float*)d_in[5];
    const float* lw      = (const float*)d_in[6];
    const float* lb      = (const float*)d_in[7];
    float* out = (float*)d_out;
    char*  ws  = (char*)d_ws;

    float*    h0    = (float*)(ws + WS_H0);
    float*    sflat = (float*)(ws + WS_SFLAT);
    float*    gpart = (float*)(ws + WS_GPART);
    float*    c0    = (float*)(ws + WS_C0);
    float*    c1    = (float*)(ws + WS_C1);
    float*    redM  = (float*)(ws + WS_REDM);
    float*    redS  = (float*)(ws + WS_REDS);
    int*      permI = (int*)(ws + WS_PERMI);
    int*      pcomI = (int*)(ws + WS_PCOMI);
    unsigned* epack = (unsigned*)(ws + WS_EPACK);
    int*      do4   = (int*)(ws + WS_DO4);
    int*      di4   = (int*)(ws + WS_DI4);
    float*    agg4  = (float*)(ws + WS_AGG4);

    k_mix<<<768, 256, 0, stream>>>(feature, W, src, dst, gpart, h0, epack, do4, di4);
    k_edgeB<<<256, 1024, 0, stream>>>(epack, h0, do4, gpart, label, agg4, c0, c1);
    k_score<<<NT / 4, 256, 0, stream>>>(feature, c0, c1, agg4, di4, label, b, lw, lb, sflat);
    k_topk<<<Bg, 512, 0, stream>>>(sflat, permI, pcomI, out, redM, redS);
    k_write<<<NT / 4, 256, 0, stream>>>(feature, permI, pcomI, sflat, redM, redS, out);
}